// Round 4
// baseline (273.335 us; speedup 1.0000x reference)
//
#include <hip/hip_runtime.h>
#include <hip/hip_bf16.h>
#include <cstdint>
#include <cstddef>

// GlobalFluxTracker: B=8, T=4096, D=256.
//   prep:  permute+convert weights to bf16 (interleaved channel layout)
//          + Ppow table: P^(r+1) for r=0..31 per channel
//   G1:    U = [x_re|x_im] @ Wm_p^T + bm_p  (reads x f32 directly)
//          + FUSED local zero-init scans (CHUNK=32) -> writes L (f32) per row
//            and chunk-finals F per (b,chunk,d).
//   scan2: parallel Hillis-Steele over 128 chunk-finals -> per-chunk init Ic
//   corr:  S = L + Ppow*Ic  (elementwise, bf16 out, fully parallel/BW-bound)
//   G2:    OUT = S @ Wc_p^T + bc, sigmoid-clip cols >= 512  (f32 out)
//          (proven global_load_lds structure, no staging VALU in A-path)

typedef __bf16 bf16;
typedef __bf16 bf16x8 __attribute__((ext_vector_type(8)));
typedef float floatx4 __attribute__((ext_vector_type(4)));

#define NB 8
#define NT 4096
#define ND 256
#define BT (NB * NT)        // 32768
#define TWOD 512
#define CHUNK 32
#define NCHUNK (NT / CHUNK) // 128

static __device__ __forceinline__ float sigmoidf_(float x) {
  return 1.0f / (1.0f + __expf(-x));
}

static __device__ __forceinline__ void async_copy16(const void* g, void* l) {
  __builtin_amdgcn_global_load_lds(
      (__attribute__((address_space(1))) void*)g,
      (__attribute__((address_space(3))) void*)l, 16, 0, 0);
}

union U32BF2 { unsigned int u; __bf16 h[2]; };

// ---------------------------------------------------------------- prep
// Interleave permutation: channel d -> cols/rows (2d, 2d+1).
__global__ void k_prep(const float* __restrict__ Wm,
                       const float* __restrict__ bm,
                       const float* __restrict__ Wo,
                       const float* __restrict__ Wg,
                       const float* __restrict__ bo,
                       const float* __restrict__ bg,
                       const float* __restrict__ decay_re,
                       const float* __restrict__ decay_im,
                       bf16* __restrict__ Wm_b,
                       bf16* __restrict__ Wc_b,
                       float* __restrict__ bm_p,
                       float* __restrict__ bc,
                       float* __restrict__ Ppow) {
  const int i = blockIdx.x * 256 + threadIdx.x; // 0..262143
  {
    const int r = i >> 9, c = i & 511;
    const int sr = (r >> 1) + (r & 1) * 256;
    Wm_b[i] = (bf16)Wm[sr * 512 + c];
  }
  {
    const int r = i >> 9, c = i & 511;
    const int sc = (c >> 1) + (c & 1) * 256;
    Wc_b[i] = (bf16)Wo[r * 512 + sc];                           // rows 0..511
    if (i < 131072) Wc_b[262144 + i] = (bf16)Wg[r * 512 + sc];  // rows 512..767
  }
  if (i < 512) { bm_p[i] = bm[(i >> 1) + (i & 1) * 256]; bc[i] = bo[i]; }
  if (i < 256) bc[512 + i] = bg[i];
  // Ppow[r*256+d] = P_d^(r+1), r=0..31 (within-chunk offset power)
  if (i < 8192) {
    const int r = i >> 8, d = i & 255;
    const float dr = sigmoidf_(decay_re[d]);
    const float di = decay_im[d];
    float wr = dr, wi = di; // P^1
    for (int j = 0; j < r; ++j) {
      const float nr = wr * dr - wi * di;
      wi = wr * di + wi * dr;
      wr = nr;
    }
    Ppow[2 * i] = wr;
    Ppow[2 * i + 1] = wi;
  }
}

// ---------------------------------------------------------------- G1 (+local scan)
__global__ __launch_bounds__(256) void gemm1(
    const float* __restrict__ xre, const float* __restrict__ xim,
    const bf16* __restrict__ Bw, const float* __restrict__ bias,
    float* __restrict__ Lf,
    const float* __restrict__ decay_re, const float* __restrict__ decay_im,
    float* __restrict__ Fre, float* __restrict__ Fim) {
  __shared__ __align__(16) bf16 smem[128 * 128]; // 32 KB
  bf16* As = smem;            // 128x64 (16 KB)
  bf16* Bs = smem + 128 * 64; // 128x64 (16 KB)
  bf16* Us = smem;            // epilogue reuse: 128x128 bf16 tile
  const int tid = threadIdx.x;
  const int wave = tid >> 6;
  const int lane = tid & 63;
  const int quad = lane >> 4;
  const int l16 = lane & 15;
  const int m0 = blockIdx.x * 128;
  const int n0 = blockIdx.y * 128;
  const int wm = (wave >> 1) * 64;
  const int wn = (wave & 1) * 64;
  const int srow = lane >> 3;
  const int schunk = (lane & 7) ^ (srow & 7);
  const int ar = tid >> 3; // 0..31
  const int sg = tid & 7;

  floatx4 acc[4][4];
#pragma unroll
  for (int i = 0; i < 4; ++i)
#pragma unroll
    for (int j = 0; j < 4; ++j) acc[i][j] = (floatx4)0.0f;

  for (int k0 = 0; k0 < 512; k0 += 64) {
    const float* xs = (k0 < 256) ? xre : xim;
    const int xcol = k0 & 255;
    __syncthreads();
    // B: async global->LDS (chunk-XOR swizzle)
#pragma unroll
    for (int i = 0; i < 4; ++i) {
      const int seg = wave * 4 + i;
      const int row = seg * 8 + srow;
      async_copy16(Bw + (size_t)(n0 + row) * 512 + k0 + schunk * 8, Bs + seg * 512);
    }
    // A: manual f32 load -> bf16 -> LDS (same swizzle)
#pragma unroll
    for (int it = 0; it < 4; ++it) {
      const int r = ar + 32 * it;
      const int cg = sg ^ (r & 7);
      const float* src = xs + (size_t)(m0 + r) * 256 + xcol + cg * 8;
      const float4 f0 = *(const float4*)(src);
      const float4 f1 = *(const float4*)(src + 4);
      bf16x8 v;
      v[0] = (bf16)f0.x; v[1] = (bf16)f0.y; v[2] = (bf16)f0.z; v[3] = (bf16)f0.w;
      v[4] = (bf16)f1.x; v[5] = (bf16)f1.y; v[6] = (bf16)f1.z; v[7] = (bf16)f1.w;
      *(bf16x8*)(As + r * 64 + sg * 8) = v;
    }
    __syncthreads();

#pragma unroll
    for (int s = 0; s < 2; ++s) {
      bf16x8 af[4], bfr[4];
#pragma unroll
      for (int mi = 0; mi < 4; ++mi) {
        const int row = wm + mi * 16 + l16;
        const int ch = ((s << 2) | quad) ^ (l16 & 7);
        af[mi] = *(const bf16x8*)(As + row * 64 + ch * 8);
      }
#pragma unroll
      for (int ni = 0; ni < 4; ++ni) {
        const int row = wn + ni * 16 + l16;
        const int ch = ((s << 2) | quad) ^ (l16 & 7);
        bfr[ni] = *(const bf16x8*)(Bs + row * 64 + ch * 8);
      }
#pragma unroll
      for (int mi = 0; mi < 4; ++mi)
#pragma unroll
        for (int ni = 0; ni < 4; ++ni)
          acc[mi][ni] = __builtin_amdgcn_mfma_f32_16x16x32_bf16(
              af[mi], bfr[ni], acc[mi][ni], 0, 0, 0);
    }
  }

  // ---- epilogue: bias add, stage bf16 tile to LDS (scan input)
  __syncthreads(); // all MFMA-feeding LDS reads done before Us overwrite
#pragma unroll
  for (int mi = 0; mi < 4; ++mi) {
    const int rloc = wm + mi * 16 + quad * 4;
#pragma unroll
    for (int ni = 0; ni < 4; ++ni) {
      const int cloc = wn + ni * 16 + l16;
      const float bb = bias[n0 + cloc];
#pragma unroll
      for (int r = 0; r < 4; ++r)
        Us[(rloc + r) * 128 + cloc] = (bf16)(acc[mi][ni][r] + bb);
    }
  }
  __syncthreads();
  // fused local scans (zero-init): 4 subchunks x 64 channels.
  // Writes L (f32 complex) per row directly to global + chunk-final F.
  {
    const int sc = tid >> 6;  // 0..3 (wave-uniform)
    const int dd = tid & 63;  // 0..63
    const int d = (n0 >> 1) + dd;
    const float drr = sigmoidf_(decay_re[d]);
    const float dii = decay_im[d];
    float sr = 0.f, si = 0.f;
    const unsigned int* Up = (const unsigned int*)(Us + (sc * 32) * 128 + 2 * dd);
    float2* Lp = (float2*)Lf + (size_t)(m0 + sc * 32) * 256 + d;
#pragma unroll 4
    for (int j = 0; j < 32; ++j) {
      U32BF2 cv; cv.u = Up[j * 64];
      const float ur = (float)cv.h[0];
      const float ui = (float)cv.h[1];
      const float nr = sr * drr - si * dii + ur;
      const float ni2 = sr * dii + si * drr + ui;
      sr = nr; si = ni2;
      Lp[(size_t)j * 256] = make_float2(nr, ni2);
    }
    const int bidx = m0 >> 12;
    const int cchunk = ((m0 & 4095) >> 5) + sc;
    const int o = (bidx * NCHUNK + cchunk) * ND + d;
    Fre[o] = sr; Fim[o] = si;
  }
}

// ---------------------------------------------------------------- scan2 (parallel)
// Per (b,d): weighted inclusive scan of F over 128 chunks, multiplier P32.
// b_c = F_c + P32*b_{c-1}; init for chunk c: I_c = b_{c-1} + P32^c * s0.
// Output interleaved complex: Ic[(b*128+c)*256+d] = (re, im).
__global__ void k_scan2(const float* __restrict__ Fre,
                        const float* __restrict__ Fim,
                        const float* __restrict__ s0_re,
                        const float* __restrict__ s0_im,
                        const float* __restrict__ decay_re,
                        const float* __restrict__ decay_im,
                        float* __restrict__ Ic) {
  const int c = threadIdx.x;  // 0..127
  const int d = blockIdx.x;   // 0..255
  const int b = blockIdx.y;   // 0..7
  const float drr = sigmoidf_(decay_re[d]);
  const float dii = decay_im[d];
  float wr = drr, wi = dii; // -> P32 via 5 squarings
#pragma unroll
  for (int i = 0; i < 5; ++i) {
    const float nr = wr * wr - wi * wi;
    const float ni = 2.f * wr * wi;
    wr = nr; wi = ni;
  }
  const int o = (b * NCHUNK + c) * ND + d;
  float vr = Fre[o], vi = Fim[o];
  float ar = 1.f, ai = 0.f;   // -> P32^c via binary decomposition of c
  __shared__ float lr[128], li[128];
#pragma unroll
  for (int k = 1; k < 128; k <<= 1) {
    lr[c] = vr; li[c] = vi;
    __syncthreads();
    const float tr = (c >= k) ? lr[c - k] : 0.f;
    const float ti = (c >= k) ? li[c - k] : 0.f;
    __syncthreads();
    vr += wr * tr - wi * ti;
    vi += wr * ti + wi * tr;
    if (c & k) {
      const float nar = ar * wr - ai * wi;
      ai = ar * wi + ai * wr;
      ar = nar;
    }
    const float nwr = wr * wr - wi * wi;
    wi = 2.f * wr * wi;
    wr = nwr;
  }
  // exclusive shift: I_c = b_{c-1} (b_{-1} = 0) + P32^c * s0
  lr[c] = vr; li[c] = vi;
  __syncthreads();
  float er = (c > 0) ? lr[c - 1] : 0.f;
  float ei = (c > 0) ? li[c - 1] : 0.f;
  const float s0r = s0_re[b * ND + d];
  const float s0i = s0_im[b * ND + d];
  er += ar * s0r - ai * s0i;
  ei += ar * s0i + ai * s0r;
  ((float2*)Ic)[o] = make_float2(er, ei);
}

// ---------------------------------------------------------------- corr
// Elementwise, fully parallel: S[r][8-group cg] = L + Ppow[(r%32)]*Ic[b,chunk].
// 32B/lane coalesced reads, 16B/lane writes. Pure BW.
__global__ __launch_bounds__(256) void k_corr(
    const float* __restrict__ Lf, const float* __restrict__ Ppow,
    const float* __restrict__ Ic, bf16* __restrict__ S) {
  const int idx = blockIdx.x * 256 + threadIdx.x; // 0..2097151
  const int r = idx >> 6;   // global row 0..32767 (= b*4096 + t)
  const int cg = idx & 63;  // chunk of 8 bf16 (= 4 complex channels)
  const int db = cg * 4;
  const float* src = Lf + (size_t)r * 512 + cg * 8;
  const float4 f0 = *(const float4*)(src);
  const float4 f1 = *(const float4*)(src + 4);
  const float4* pwp = (const float4*)(Ppow + 2 * ((r & 31) * 256 + db));
  const float4 p0 = pwp[0], p1 = pwp[1];
  const int c = r >> 5;     // = b*128 + t/32
  const float4* icp = (const float4*)(Ic + 2 * ((size_t)c * 256 + db));
  const float4 i0 = icp[0], i1 = icp[1];
  bf16x8 v;
  v[0] = (bf16)(f0.x + p0.x * i0.x - p0.y * i0.y);
  v[1] = (bf16)(f0.y + p0.x * i0.y + p0.y * i0.x);
  v[2] = (bf16)(f0.z + p0.z * i0.z - p0.w * i0.w);
  v[3] = (bf16)(f0.w + p0.z * i0.w + p0.w * i0.z);
  v[4] = (bf16)(f1.x + p1.x * i1.x - p1.y * i1.y);
  v[5] = (bf16)(f1.y + p1.x * i1.y + p1.y * i1.x);
  v[6] = (bf16)(f1.z + p1.z * i1.z - p1.w * i1.w);
  v[7] = (bf16)(f1.w + p1.z * i1.w + p1.w * i1.z);
  *(bf16x8*)(S + (size_t)r * 512 + cg * 8) = v;
}

// ---------------------------------------------------------------- G2
// Proven structure: both operands bf16 via global_load_lds, XOR swizzle,
// 128x128 tile, grid (256, 6).
__global__ __launch_bounds__(256) void gemm2(
    const bf16* __restrict__ A, const bf16* __restrict__ Bw,
    const float* __restrict__ bias, float* __restrict__ C) {
  __shared__ __align__(16) bf16 As[128 * 64]; // 16 KB
  __shared__ __align__(16) bf16 Bs[128 * 64]; // 16 KB
  const int tid = threadIdx.x;
  const int wave = tid >> 6;
  const int lane = tid & 63;
  const int quad = lane >> 4;
  const int l16 = lane & 15;
  const int m0 = blockIdx.x * 128;
  const int n0 = blockIdx.y * 128;
  const int wm = (wave >> 1) * 64;
  const int wn = (wave & 1) * 64;
  const int srow = lane >> 3;
  const int schunk = (lane & 7) ^ (srow & 7);

  floatx4 acc[4][4];
#pragma unroll
  for (int i = 0; i < 4; ++i)
#pragma unroll
    for (int j = 0; j < 4; ++j) acc[i][j] = (floatx4)0.0f;

  for (int k0 = 0; k0 < 512; k0 += 64) {
    __syncthreads();
#pragma unroll
    for (int i = 0; i < 4; ++i) {
      const int seg = wave * 4 + i;
      const int row = seg * 8 + srow;
      async_copy16(A + (size_t)(m0 + row) * 512 + k0 + schunk * 8, As + seg * 512);
    }
#pragma unroll
    for (int i = 0; i < 4; ++i) {
      const int seg = wave * 4 + i;
      const int row = seg * 8 + srow;
      async_copy16(Bw + (size_t)(n0 + row) * 512 + k0 + schunk * 8, Bs + seg * 512);
    }
    __syncthreads();

#pragma unroll
    for (int s = 0; s < 2; ++s) {
      bf16x8 af[4], bfr[4];
#pragma unroll
      for (int mi = 0; mi < 4; ++mi) {
        const int row = wm + mi * 16 + l16;
        const int ch = ((s << 2) | quad) ^ (l16 & 7);
        af[mi] = *(const bf16x8*)(As + row * 64 + ch * 8);
      }
#pragma unroll
      for (int ni = 0; ni < 4; ++ni) {
        const int row = wn + ni * 16 + l16;
        const int ch = ((s << 2) | quad) ^ (l16 & 7);
        bfr[ni] = *(const bf16x8*)(Bs + row * 64 + ch * 8);
      }
#pragma unroll
      for (int mi = 0; mi < 4; ++mi)
#pragma unroll
        for (int ni = 0; ni < 4; ++ni)
          acc[mi][ni] = __builtin_amdgcn_mfma_f32_16x16x32_bf16(
              af[mi], bfr[ni], acc[mi][ni], 0, 0, 0);
    }
  }

#pragma unroll
  for (int mi = 0; mi < 4; ++mi) {
    const int rb = m0 + wm + mi * 16 + quad * 4;
#pragma unroll
    for (int ni = 0; ni < 4; ++ni) {
      const int col = n0 + wn + ni * 16 + l16;
      const float bb = bias[col];
#pragma unroll
      for (int r = 0; r < 4; ++r) {
        float v = acc[mi][ni][r] + bb;
        if (col >= 512) v = fminf(fmaxf(sigmoidf_(v), 0.01f), 0.99f);
        C[(size_t)(rb + r) * 768 + col] = v;
      }
    }
  }
}

// ---------------------------------------------------------------- launch

extern "C" void kernel_launch(void* const* d_in, const int* in_sizes, int n_in,
                              void* d_out, int out_size, void* d_ws, size_t ws_size,
                              hipStream_t stream) {
  const float* x_re = (const float*)d_in[0];
  const float* x_im = (const float*)d_in[1];
  const float* s0_re = (const float*)d_in[2];
  const float* s0_im = (const float*)d_in[3];
  const float* decay_re = (const float*)d_in[4];
  const float* decay_im = (const float*)d_in[5];
  const float* Wm = (const float*)d_in[6];
  const float* bm = (const float*)d_in[7];
  const float* Wo = (const float*)d_in[8];
  const float* bo = (const float*)d_in[9];
  const float* Wg = (const float*)d_in[10];
  const float* bg = (const float*)d_in[11];

  char* ws = (char*)d_ws;
  const size_t L_OFF = 0;                        // 64 MB (32768 x 512 f32)
  const size_t S_OFF = 67108864;                 // 32 MB (32768 x 512 bf16)
  const size_t WM_OFF = S_OFF + 33554432;        // 512 KB
  const size_t WC_OFF = WM_OFF + 524288;         // 768 KB
  const size_t BMP_OFF = WC_OFF + 786432;        // 2 KB (+pad)
  const size_t BC_OFF = BMP_OFF + 4096;          // 3 KB (+pad)
  const size_t FRE_OFF = BC_OFF + 4096;          // 1 MB each
  const size_t FIM_OFF = FRE_OFF + 1048576;
  const size_t IC_OFF = FIM_OFF + 1048576;       // 2 MB (interleaved complex)
  const size_t PPOW_OFF = IC_OFF + 2097152;      // 64 KB

  float* Lf = (float*)(ws + L_OFF);
  bf16* Sb = (bf16*)(ws + S_OFF);
  bf16* Wm_b = (bf16*)(ws + WM_OFF);
  bf16* Wc_b = (bf16*)(ws + WC_OFF);
  float* bm_p = (float*)(ws + BMP_OFF);
  float* bc = (float*)(ws + BC_OFF);
  float* Fre = (float*)(ws + FRE_OFF);
  float* Fim = (float*)(ws + FIM_OFF);
  float* Ic = (float*)(ws + IC_OFF);
  float* Ppow = (float*)(ws + PPOW_OFF);

  k_prep<<<dim3(1024), 256, 0, stream>>>(Wm, bm, Wo, Wg, bo, bg,
                                         decay_re, decay_im,
                                         Wm_b, Wc_b, bm_p, bc, Ppow);
  gemm1<<<dim3(256, 4), 256, 0, stream>>>(x_re, x_im, Wm_b, bm_p, Lf,
                                          decay_re, decay_im, Fre, Fim);
  k_scan2<<<dim3(ND, NB), NCHUNK, 0, stream>>>(Fre, Fim, s0_re, s0_im,
                                               decay_re, decay_im, Ic);
  k_corr<<<dim3(8192), 256, 0, stream>>>(Lf, Ppow, Ic, Sb);
  gemm2<<<dim3(256, 6), 256, 0, stream>>>(Sb, Wc_b, bc, (float*)d_out);
}

// Round 5
// 242.827 us; speedup vs baseline: 1.1256x; 1.1256x over previous
//
#include <hip/hip_runtime.h>
#include <hip/hip_bf16.h>
#include <cstdint>
#include <cstddef>

// GlobalFluxTracker: B=8, T=4096, D=256.
//   prep:  permute+convert weights to bf16 (interleaved channel layout)
//   G1:    U = [x_re|x_im] @ Wm_p^T + bm_p  (reads x f32 directly, bf16 out)
//          + FUSED local chunk scans (CHUNK=32, zero-init) -> F per (b,chunk,d)
//          [XCD-chunked swizzle: 4 n-blocks of an x-panel share an XCD L2]
//   scan2: parallel Hillis-Steele over 128 chunk-finals -> per-chunk init I
//   pass3: recompute local scans with true init, in-place U -> S (bf16)
//   G2:    OUT = S @ Wc_p^T + bc, sigmoid-clip cols >= 512  (f32 out)
//          [XCD-chunked swizzle, n-fastest: 12 n-blocks of an S-panel run
//           dispatch-adjacent on one XCD; 32 panels/chunk = 4MB = L2 size]

typedef __bf16 bf16;
typedef __bf16 bf16x8 __attribute__((ext_vector_type(8)));
typedef float floatx4 __attribute__((ext_vector_type(4)));

#define NB 8
#define NT 4096
#define ND 256
#define BT (NB * NT)        // 32768
#define TWOD 512
#define CHUNK 32
#define NCHUNK (NT / CHUNK) // 128

static __device__ __forceinline__ float sigmoidf_(float x) {
  return 1.0f / (1.0f + __expf(-x));
}

static __device__ __forceinline__ void async_copy16(const void* g, void* l) {
  __builtin_amdgcn_global_load_lds(
      (__attribute__((address_space(1))) void*)g,
      (__attribute__((address_space(3))) void*)l, 16, 0, 0);
}

union U32BF2 { unsigned int u; __bf16 h[2]; };

// ---------------------------------------------------------------- prep
// Interleave permutation: channel d -> cols/rows (2d, 2d+1).
__global__ void k_prep(const float* __restrict__ Wm,
                       const float* __restrict__ bm,
                       const float* __restrict__ Wo,
                       const float* __restrict__ Wg,
                       const float* __restrict__ bo,
                       const float* __restrict__ bg,
                       bf16* __restrict__ Wm_b,
                       bf16* __restrict__ Wc_b,
                       float* __restrict__ bm_p,
                       float* __restrict__ bc) {
  const int i = blockIdx.x * 256 + threadIdx.x; // 0..262143
  {
    const int r = i >> 9, c = i & 511;
    const int sr = (r >> 1) + (r & 1) * 256;
    Wm_b[i] = (bf16)Wm[sr * 512 + c];
  }
  {
    const int r = i >> 9, c = i & 511;
    const int sc = (c >> 1) + (c & 1) * 256;
    Wc_b[i] = (bf16)Wo[r * 512 + sc];                           // rows 0..511
    if (i < 131072) Wc_b[262144 + i] = (bf16)Wg[r * 512 + sc];  // rows 512..767
  }
  if (i < 512) { bm_p[i] = bm[(i >> 1) + (i & 1) * 256]; bc[i] = bo[i]; }
  if (i < 256) bc[512 + i] = bg[i];
}

// ---------------------------------------------------------------- G1 (+local scan)
// 1-D grid 1024, XCD-chunked: nb = (bid%8)*128 + bid/8; m = nb/4, n = nb%4.
__global__ __launch_bounds__(256) void gemm1(
    const float* __restrict__ xre, const float* __restrict__ xim,
    const bf16* __restrict__ Bw, const float* __restrict__ bias,
    bf16* __restrict__ Cu,
    const float* __restrict__ decay_re, const float* __restrict__ decay_im,
    float* __restrict__ Fre, float* __restrict__ Fim) {
  __shared__ __align__(16) bf16 smem[128 * 128]; // 32 KB
  bf16* As = smem;            // 128x64 (16 KB)
  bf16* Bs = smem + 128 * 64; // 128x64 (16 KB)
  bf16* Us = smem;            // epilogue reuse: 128x128 bf16 tile
  const int tid = threadIdx.x;
  const int wave = tid >> 6;
  const int lane = tid & 63;
  const int quad = lane >> 4;
  const int l16 = lane & 15;
  const int bid = blockIdx.x;
  const int nb = (bid & 7) * 128 + (bid >> 3); // bijective XCD chunk (1024%8==0)
  const int m0 = (nb >> 2) * 128;  // n-fastest: 4 n-blocks of a panel adjacent
  const int n0 = (nb & 3) * 128;
  const int wm = (wave >> 1) * 64;
  const int wn = (wave & 1) * 64;
  const int srow = lane >> 3;
  const int schunk = (lane & 7) ^ (srow & 7);
  const int ar = tid >> 3; // 0..31
  const int sg = tid & 7;

  floatx4 acc[4][4];
#pragma unroll
  for (int i = 0; i < 4; ++i)
#pragma unroll
    for (int j = 0; j < 4; ++j) acc[i][j] = (floatx4)0.0f;

  for (int k0 = 0; k0 < 512; k0 += 64) {
    const float* xs = (k0 < 256) ? xre : xim;
    const int xcol = k0 & 255;
    __syncthreads();
    // B: async global->LDS (chunk-XOR swizzle)
#pragma unroll
    for (int i = 0; i < 4; ++i) {
      const int seg = wave * 4 + i;
      const int row = seg * 8 + srow;
      async_copy16(Bw + (size_t)(n0 + row) * 512 + k0 + schunk * 8, Bs + seg * 512);
    }
    // A: manual f32 load -> bf16 -> LDS (same swizzle)
#pragma unroll
    for (int it = 0; it < 4; ++it) {
      const int r = ar + 32 * it;
      const int cg = sg ^ (r & 7);
      const float* src = xs + (size_t)(m0 + r) * 256 + xcol + cg * 8;
      const float4 f0 = *(const float4*)(src);
      const float4 f1 = *(const float4*)(src + 4);
      bf16x8 v;
      v[0] = (bf16)f0.x; v[1] = (bf16)f0.y; v[2] = (bf16)f0.z; v[3] = (bf16)f0.w;
      v[4] = (bf16)f1.x; v[5] = (bf16)f1.y; v[6] = (bf16)f1.z; v[7] = (bf16)f1.w;
      *(bf16x8*)(As + r * 64 + sg * 8) = v;
    }
    __syncthreads();

#pragma unroll
    for (int s = 0; s < 2; ++s) {
      bf16x8 af[4], bfr[4];
#pragma unroll
      for (int mi = 0; mi < 4; ++mi) {
        const int row = wm + mi * 16 + l16;
        const int ch = ((s << 2) | quad) ^ (l16 & 7);
        af[mi] = *(const bf16x8*)(As + row * 64 + ch * 8);
      }
#pragma unroll
      for (int ni = 0; ni < 4; ++ni) {
        const int row = wn + ni * 16 + l16;
        const int ch = ((s << 2) | quad) ^ (l16 & 7);
        bfr[ni] = *(const bf16x8*)(Bs + row * 64 + ch * 8);
      }
#pragma unroll
      for (int mi = 0; mi < 4; ++mi)
#pragma unroll
        for (int ni = 0; ni < 4; ++ni)
          acc[mi][ni] = __builtin_amdgcn_mfma_f32_16x16x32_bf16(
              af[mi], bfr[ni], acc[mi][ni], 0, 0, 0);
    }
  }

  // ---- epilogue: bias add, stage bf16 tile to LDS
  __syncthreads(); // all MFMA-feeding LDS reads done before Us overwrite
#pragma unroll
  for (int mi = 0; mi < 4; ++mi) {
    const int rloc = wm + mi * 16 + quad * 4;
#pragma unroll
    for (int ni = 0; ni < 4; ++ni) {
      const int cloc = wn + ni * 16 + l16;
      const float bb = bias[n0 + cloc];
#pragma unroll
      for (int r = 0; r < 4; ++r)
        Us[(rloc + r) * 128 + cloc] = (bf16)(acc[mi][ni][r] + bb);
    }
  }
  __syncthreads();
  // coalesced b128 global store of U from LDS
  {
    bf16* dst = Cu + (size_t)m0 * TWOD + n0;
#pragma unroll
    for (int i = 0; i < 8; ++i) {
      const int e = i * 256 + tid;   // 16B-chunk index 0..2047
      const int row = e >> 4, ch = e & 15;
      *(bf16x8*)(dst + (size_t)row * TWOD + ch * 8) =
          *(const bf16x8*)(Us + row * 128 + ch * 8);
    }
  }
  // fused local scans (zero-init): 4 subchunks x 64 channels
  {
    const int sc = tid >> 6;  // 0..3 (wave-uniform)
    const int dd = tid & 63;  // 0..63
    const int d = (n0 >> 1) + dd;
    const float drr = sigmoidf_(decay_re[d]);
    const float dii = decay_im[d];
    float sr = 0.f, si = 0.f;
    const unsigned int* Up = (const unsigned int*)(Us + (sc * 32) * 128 + 2 * dd);
#pragma unroll 4
    for (int j = 0; j < 32; ++j) {
      U32BF2 cv; cv.u = Up[j * 64];
      const float ur = (float)cv.h[0];
      const float ui = (float)cv.h[1];
      const float nr = sr * drr - si * dii + ur;
      const float ni2 = sr * dii + si * drr + ui;
      sr = nr; si = ni2;
    }
    const int bidx = m0 >> 12;
    const int cchunk = ((m0 & 4095) >> 5) + sc;
    const int o = (bidx * NCHUNK + cchunk) * ND + d;
    Fre[o] = sr; Fim[o] = si;
  }
}

// ---------------------------------------------------------------- scan2 (parallel)
// Per (b,d): weighted inclusive scan of F over 128 chunks, multiplier P32.
// b_c = F_c + P32*b_{c-1}; init for chunk c: I_c = b_{c-1} + P32^c * s0.
__global__ void k_scan2(const float* __restrict__ Fre,
                        const float* __restrict__ Fim,
                        const float* __restrict__ s0_re,
                        const float* __restrict__ s0_im,
                        const float* __restrict__ decay_re,
                        const float* __restrict__ decay_im,
                        float* __restrict__ Ire, float* __restrict__ Iim) {
  const int c = threadIdx.x;  // 0..127
  const int d = blockIdx.x;   // 0..255
  const int b = blockIdx.y;   // 0..7
  const float drr = sigmoidf_(decay_re[d]);
  const float dii = decay_im[d];
  float wr = drr, wi = dii; // -> P32 via 5 squarings
#pragma unroll
  for (int i = 0; i < 5; ++i) {
    const float nr = wr * wr - wi * wi;
    const float ni = 2.f * wr * wi;
    wr = nr; wi = ni;
  }
  const int o = (b * NCHUNK + c) * ND + d;
  float vr = Fre[o], vi = Fim[o];
  float ar = 1.f, ai = 0.f;   // -> P32^c via binary decomposition of c
  __shared__ float lr[128], li[128];
#pragma unroll
  for (int k = 1; k < 128; k <<= 1) {
    lr[c] = vr; li[c] = vi;
    __syncthreads();
    const float tr = (c >= k) ? lr[c - k] : 0.f;
    const float ti = (c >= k) ? li[c - k] : 0.f;
    __syncthreads();
    vr += wr * tr - wi * ti;
    vi += wr * ti + wi * tr;
    if (c & k) {
      const float nar = ar * wr - ai * wi;
      ai = ar * wi + ai * wr;
      ar = nar;
    }
    const float nwr = wr * wr - wi * wi;
    wi = 2.f * wr * wi;
    wr = nwr;
  }
  // exclusive shift: I_c = b_{c-1} (b_{-1} = 0) + P32^c * s0
  lr[c] = vr; li[c] = vi;
  __syncthreads();
  float er = (c > 0) ? lr[c - 1] : 0.f;
  float ei = (c > 0) ? li[c - 1] : 0.f;
  const float s0r = s0_re[b * ND + d];
  const float s0i = s0_im[b * ND + d];
  er += ar * s0r - ai * s0i;
  ei += ar * s0i + ai * s0r;
  Ire[o] = er; Iim[o] = ei;
}

// ---------------------------------------------------------------- pass3
__global__ void k_scan_pass3(bf16* __restrict__ U,
                             const float* __restrict__ decay_re,
                             const float* __restrict__ decay_im,
                             const float* __restrict__ Ire,
                             const float* __restrict__ Iim) {
  const int d = threadIdx.x;
  const int c = blockIdx.x;
  const int b = blockIdx.y;
  const float dr = sigmoidf_(decay_re[d]);
  const float di = decay_im[d];
  const int o = (b * NCHUNK + c) * ND + d;
  float sr = Ire[o], si = Iim[o];
  unsigned int* Ur = (unsigned int*)
      (U + ((size_t)b * NT + (size_t)c * CHUNK) * TWOD + 2 * d);
#pragma unroll 4
  for (int j = 0; j < CHUNK; ++j) {
    U32BF2 cv; cv.u = Ur[(size_t)j * (TWOD / 2)];
    const float ur = (float)cv.h[0];
    const float ui = (float)cv.h[1];
    const float nr = sr * dr - si * di + ur;
    const float ni = sr * di + si * dr + ui;
    sr = nr; si = ni;
    cv.h[0] = (bf16)nr; cv.h[1] = (bf16)ni;
    Ur[(size_t)j * (TWOD / 2)] = cv.u;
  }
}

// ---------------------------------------------------------------- G2
// 1-D grid 3072, XCD-chunked n-fastest: nb = (bid%8)*384 + bid/8;
// m = nb/12, n = nb%12 -> 12 n-blocks of one S-panel dispatch-adjacent on one
// XCD; a 384-block chunk spans 32 panels = 4MB S (L2-resident per XCD).
__global__ __launch_bounds__(256) void gemm2(
    const bf16* __restrict__ A, const bf16* __restrict__ Bw,
    const float* __restrict__ bias, float* __restrict__ C) {
  __shared__ __align__(16) bf16 As[128 * 64]; // 16 KB
  __shared__ __align__(16) bf16 Bs[64 * 64];  // 8 KB
  const int tid = threadIdx.x;
  const int wave = tid >> 6;
  const int lane = tid & 63;
  const int quad = lane >> 4;
  const int l16 = lane & 15;
  const int bid = blockIdx.x;
  const int nb = (bid & 7) * 384 + (bid >> 3); // bijective (3072%8==0)
  const int m0 = (nb / 12) * 128;
  const int n0 = (nb % 12) * 64;
  const int wm = (wave >> 1) * 64;
  const int wn = (wave & 1) * 32;
  const int srow = lane >> 3;
  const int schunk = (lane & 7) ^ (srow & 7);

  floatx4 acc[4][2];
#pragma unroll
  for (int i = 0; i < 4; ++i)
#pragma unroll
    for (int j = 0; j < 2; ++j) acc[i][j] = (floatx4)0.0f;

  for (int k0 = 0; k0 < 512; k0 += 64) {
    __syncthreads();
#pragma unroll
    for (int i = 0; i < 4; ++i) {
      const int seg = wave * 4 + i;
      const int row = seg * 8 + srow;
      async_copy16(A + (size_t)(m0 + row) * 512 + k0 + schunk * 8, As + seg * 512);
    }
#pragma unroll
    for (int i = 0; i < 2; ++i) {
      const int seg = wave * 2 + i;
      const int row = seg * 8 + srow;
      async_copy16(Bw + (size_t)(n0 + row) * 512 + k0 + schunk * 8, Bs + seg * 512);
    }
    __syncthreads();

#pragma unroll
    for (int s = 0; s < 2; ++s) {
      bf16x8 af[4], bfr[2];
#pragma unroll
      for (int mi = 0; mi < 4; ++mi) {
        const int row = wm + mi * 16 + l16;
        const int ch = ((s << 2) | quad) ^ (l16 & 7);
        af[mi] = *(const bf16x8*)(As + row * 64 + ch * 8);
      }
#pragma unroll
      for (int ni = 0; ni < 2; ++ni) {
        const int row = wn + ni * 16 + l16;
        const int ch = ((s << 2) | quad) ^ (l16 & 7);
        bfr[ni] = *(const bf16x8*)(Bs + row * 64 + ch * 8);
      }
#pragma unroll
      for (int mi = 0; mi < 4; ++mi)
#pragma unroll
        for (int ni = 0; ni < 2; ++ni)
          acc[mi][ni] = __builtin_amdgcn_mfma_f32_16x16x32_bf16(
              af[mi], bfr[ni], acc[mi][ni], 0, 0, 0);
    }
  }

#pragma unroll
  for (int mi = 0; mi < 4; ++mi) {
    const int rb = m0 + wm + mi * 16 + quad * 4;
#pragma unroll
    for (int ni = 0; ni < 2; ++ni) {
      const int col = n0 + wn + ni * 16 + l16;
      const float bb = bias[col];
#pragma unroll
      for (int r = 0; r < 4; ++r) {
        float v = acc[mi][ni][r] + bb;
        if (col >= 512) v = fminf(fmaxf(sigmoidf_(v), 0.01f), 0.99f);
        C[(size_t)(rb + r) * 768 + col] = v;
      }
    }
  }
}

// ---------------------------------------------------------------- launch

extern "C" void kernel_launch(void* const* d_in, const int* in_sizes, int n_in,
                              void* d_out, int out_size, void* d_ws, size_t ws_size,
                              hipStream_t stream) {
  const float* x_re = (const float*)d_in[0];
  const float* x_im = (const float*)d_in[1];
  const float* s0_re = (const float*)d_in[2];
  const float* s0_im = (const float*)d_in[3];
  const float* decay_re = (const float*)d_in[4];
  const float* decay_im = (const float*)d_in[5];
  const float* Wm = (const float*)d_in[6];
  const float* bm = (const float*)d_in[7];
  const float* Wo = (const float*)d_in[8];
  const float* bo = (const float*)d_in[9];
  const float* Wg = (const float*)d_in[10];
  const float* bg = (const float*)d_in[11];

  char* ws = (char*)d_ws;
  const size_t U_OFF = 0;                      // 32 MB
  const size_t WM_OFF = 33554432;              // 512 KB
  const size_t WC_OFF = WM_OFF + 524288;       // 768 KB
  const size_t BMP_OFF = WC_OFF + 786432;      // 2 KB (+pad)
  const size_t BC_OFF = BMP_OFF + 4096;        // 3 KB (+pad)
  const size_t FRE_OFF = BC_OFF + 4096;        // 1 MB each
  const size_t FIM_OFF = FRE_OFF + 1048576;
  const size_t IRE_OFF = FIM_OFF + 1048576;
  const size_t IIM_OFF = IRE_OFF + 1048576;

  bf16* U = (bf16*)(ws + U_OFF);
  bf16* Wm_b = (bf16*)(ws + WM_OFF);
  bf16* Wc_b = (bf16*)(ws + WC_OFF);
  float* bm_p = (float*)(ws + BMP_OFF);
  float* bc = (float*)(ws + BC_OFF);
  float* Fre = (float*)(ws + FRE_OFF);
  float* Fim = (float*)(ws + FIM_OFF);
  float* Ire = (float*)(ws + IRE_OFF);
  float* Iim = (float*)(ws + IIM_OFF);

  k_prep<<<dim3(1024), 256, 0, stream>>>(Wm, bm, Wo, Wg, bo, bg,
                                         Wm_b, Wc_b, bm_p, bc);
  gemm1<<<dim3(1024), 256, 0, stream>>>(x_re, x_im, Wm_b, bm_p, U,
                                        decay_re, decay_im, Fre, Fim);
  k_scan2<<<dim3(ND, NB), NCHUNK, 0, stream>>>(Fre, Fim, s0_re, s0_im,
                                               decay_re, decay_im, Ire, Iim);
  k_scan_pass3<<<dim3(NCHUNK, NB), ND, 0, stream>>>(U, decay_re, decay_im, Ire, Iim);
  gemm2<<<dim3(3072), 256, 0, stream>>>(U, Wc_b, bc, (float*)d_out);
}